// Round 1
// baseline (354.501 us; speedup 1.0000x reference)
//
#include <hip/hip_runtime.h>

// Problem constants: B=8, N=1024, C=64, O=64, K+1=4
#define EPS_Q 1e-12f

__device__ __forceinline__ float wave_reduce_sum(float v) {
#pragma unroll
    for (int m = 32; m > 0; m >>= 1) v += __shfl_xor(v, m, 64);
    return v;
}

// ---------------------------------------------------------------------------
// Kernel A: per-node attention scores. One wave per row (b*N+n), lane = c.
// sR_i = Xr·Wr_i - Xi·Wi_i ; sI_i = Xr·Wi_i + Xi·Wr_i ; same with _j weights.
// Writes sRi/sIi arrays and aux[row].x/.y = (sRj, sIj).
// ---------------------------------------------------------------------------
__global__ __launch_bounds__(256)
void k_scores(const float* __restrict__ Xr, const float* __restrict__ Xi,
              const float* __restrict__ awr, const float* __restrict__ awi,
              float* __restrict__ sRi, float* __restrict__ sIi,
              float4* __restrict__ aux) {
    const int lane = threadIdx.x & 63;
    const int row  = (blockIdx.x << 2) + (threadIdx.x >> 6);  // b*N + n
    const float xr = Xr[row * 64 + lane];
    const float xi = Xi[row * 64 + lane];
    const float wri = awr[lane], wrj = awr[64 + lane];
    const float wii = awi[lane], wij = awi[64 + lane];
    float v0 = xr * wri - xi * wii;   // sR_i partial
    float v1 = xr * wii + xi * wri;   // sI_i partial
    float v2 = xr * wrj - xi * wij;   // sR_j partial
    float v3 = xr * wij + xi * wrj;   // sI_j partial
#pragma unroll
    for (int m = 32; m > 0; m >>= 1) {
        v0 += __shfl_xor(v0, m, 64);
        v1 += __shfl_xor(v1, m, 64);
        v2 += __shfl_xor(v2, m, 64);
        v3 += __shfl_xor(v3, m, 64);
    }
    if (lane == 0) {
        sRi[row] = v0;
        sIi[row] = v1;
        aux[row].x = v2;
        aux[row].y = v3;
    }
}

// ---------------------------------------------------------------------------
// Kernel B: column softmax stats. softmax is over axis=1 (index i) for each
// (b, j). One wave per (b, j); lanes stride over i, 16 mags kept in regs.
// Writes aux[row].z = colmax, aux[row].w = 1/sum(exp(mag - colmax)).
// ---------------------------------------------------------------------------
__global__ __launch_bounds__(256)
void k_softmax(const float* __restrict__ sRi, const float* __restrict__ sIi,
               float4* __restrict__ aux,
               const float* __restrict__ abr, const float* __restrict__ abi,
               const float* __restrict__ par_, const float* __restrict__ pai_) {
    const int lane = threadIdx.x & 63;
    const int row  = (blockIdx.x << 2) + (threadIdx.x >> 6);  // b*N + j
    const int b    = row >> 10;
    const float br = abr[0], bi = abi[0], par = par_[0], pai = pai_[0];
    const float sRj = aux[row].x, sIj = aux[row].y;
    const float* pR = sRi + (b << 10);
    const float* pI = sIi + (b << 10);
    float mags[16];
    float mx = -3.4e38f;
#pragma unroll
    for (int t = 0; t < 16; ++t) {
        const int i = (t << 6) + lane;
        float sr = pR[i] + sRj + br;
        float si = pI[i] + sIj + bi;
        float pr = sr >= 0.f ? sr : par * sr;
        float pi = si >= 0.f ? si : pai * si;
        float mg = sqrtf(pr * pr + pi * pi);
        mags[t] = mg;
        mx = fmaxf(mx, mg);
    }
#pragma unroll
    for (int m = 32; m > 0; m >>= 1) mx = fmaxf(mx, __shfl_xor(mx, m, 64));
    float s = 0.f;
#pragma unroll
    for (int t = 0; t < 16; ++t) s += __expf(mags[t] - mx);
    s = wave_reduce_sum(s);
    if (lane == 0) {
        aux[row].z = mx;
        aux[row].w = 1.f / s;
    }
}

// ---------------------------------------------------------------------------
// Kernel C: THE memory-bound kernel. rowR[b,k,i] = sum_j Lr*ar - Li*ai,
// rowI[b,k,i] = sum_j Lr*ai + Li*ar. One wave per (b,i). Lanes stream j with
// float4 loads (16B/lane), ar/ai recomputed once per j and reused for all 4 k.
// Reads 268 MB of L exactly once -> HBM roofline.
// ---------------------------------------------------------------------------
__global__ __launch_bounds__(256)
void k_rowreduce(const float* __restrict__ Lr, const float* __restrict__ Li,
                 const float* __restrict__ sRi, const float* __restrict__ sIi,
                 const float4* __restrict__ aux,
                 const float* __restrict__ abr, const float* __restrict__ abi,
                 const float* __restrict__ par_, const float* __restrict__ pai_,
                 float* __restrict__ rowR, float* __restrict__ rowI) {
    const int lane = threadIdx.x & 63;
    const int row  = (blockIdx.x << 2) + (threadIdx.x >> 6);  // b*N + i
    const int b = row >> 10;
    const int i = row & 1023;
    const float br = abr[0], bi = abi[0], par = par_[0], pai = pai_[0];
    const float sri = sRi[row], sii = sIi[row];
    const float4* auxb = aux + (b << 10);
    const size_t base = ((size_t)((b * 4) * 1024 + i)) * 1024;  // k=0 row start
    const float4* LR = (const float4*)(Lr + base);
    const float4* LI = (const float4*)(Li + base);
    const int kstr = (1024 * 1024) / 4;  // float4 stride between k slices
    float aR[4] = {0.f, 0.f, 0.f, 0.f};
    float aI[4] = {0.f, 0.f, 0.f, 0.f};
#pragma unroll
    for (int t = 0; t < 4; ++t) {
        const int j4 = (t << 6) + lane;  // float4 index; covers j = 4*j4..4*j4+3
        float arj[4], aij[4];
#pragma unroll
        for (int u = 0; u < 4; ++u) {
            const float4 ax = auxb[(j4 << 2) + u];  // (sRj, sIj, colmax, 1/sum)
            float sr = sri + ax.x + br;
            float si = sii + ax.y + bi;
            float pr = sr >= 0.f ? sr : par * sr;
            float pi = si >= 0.f ? si : pai * si;
            float mg = sqrtf(pr * pr + pi * pi);
            float sc = __expf(mg - ax.z) * ax.w / (mg + EPS_Q);
            arj[u] = sc * pr;
            aij[u] = sc * pi;
        }
#pragma unroll
        for (int k = 0; k < 4; ++k) {
            const float4 lr = LR[k * kstr + j4];
            const float4 li = LI[k * kstr + j4];
            aR[k] += lr.x * arj[0] - li.x * aij[0];
            aR[k] += lr.y * arj[1] - li.y * aij[1];
            aR[k] += lr.z * arj[2] - li.z * aij[2];
            aR[k] += lr.w * arj[3] - li.w * aij[3];
            aI[k] += lr.x * aij[0] + li.x * arj[0];
            aI[k] += lr.y * aij[1] + li.y * arj[1];
            aI[k] += lr.z * aij[2] + li.z * arj[2];
            aI[k] += lr.w * aij[3] + li.w * arj[3];
        }
    }
#pragma unroll
    for (int m = 32; m > 0; m >>= 1) {
#pragma unroll
        for (int k = 0; k < 4; ++k) {
            aR[k] += __shfl_xor(aR[k], m, 64);
            aI[k] += __shfl_xor(aI[k], m, 64);
        }
    }
    if (lane == 0) {
#pragma unroll
        for (int k = 0; k < 4; ++k) {
            rowR[((b << 2) + k) * 1024 + i] = aR[k];
            rowI[((b << 2) + k) * 1024 + i] = aI[k];
        }
    }
}

// ---------------------------------------------------------------------------
// Kernel D: out[b,j,o] = sum_m rowR[b,m,j]*(Xr[b,j]·wr[m,:,o])
//                      - sum_m rowI[b,m,j]*(Xi[b,j]·wi[m,:,o])   (real)
//           imag analogous. One wave handles 4 rows (register blocked) so the
//           128 KB of w is amortized; X rows staged in LDS (broadcast reads).
// ---------------------------------------------------------------------------
__global__ __launch_bounds__(256)
void k_output(const float* __restrict__ Xr, const float* __restrict__ Xi,
              const float* __restrict__ wr, const float* __restrict__ wi,
              const float* __restrict__ rowR, const float* __restrict__ rowI,
              float* __restrict__ out) {
    __shared__ float lxr[16][64];
    __shared__ float lxi[16][64];
    const int tid = threadIdx.x;
    const int rb  = blockIdx.x << 4;  // 16 rows per block
    {
        const float4* s0 = (const float4*)(Xr + (size_t)rb * 64);
        const float4* s1 = (const float4*)(Xi + (size_t)rb * 64);
        ((float4*)&lxr[0][0])[tid] = s0[tid];  // 16*64 floats = 256 float4
        ((float4*)&lxi[0][0])[tid] = s1[tid];
    }
    __syncthreads();
    const int wave = tid >> 6, lane = tid & 63;
    const int r0 = wave << 2;  // 4 rows per wave
    float u[4][4], v[4][4];
#pragma unroll
    for (int r = 0; r < 4; ++r)
#pragma unroll
        for (int m = 0; m < 4; ++m) { u[r][m] = 0.f; v[r][m] = 0.f; }
    for (int c = 0; c < 64; ++c) {
        float wrv[4], wiv[4];
#pragma unroll
        for (int m = 0; m < 4; ++m) {
            wrv[m] = wr[((m << 6) + c) * 64 + lane];
            wiv[m] = wi[((m << 6) + c) * 64 + lane];
        }
#pragma unroll
        for (int r = 0; r < 4; ++r) {
            const float xr = lxr[r0 + r][c];
            const float xi = lxi[r0 + r][c];
#pragma unroll
            for (int m = 0; m < 4; ++m) {
                u[r][m] += xr * wrv[m];
                v[r][m] += xi * wiv[m];
            }
        }
    }
#pragma unroll
    for (int r = 0; r < 4; ++r) {
        const int row = rb + r0 + r;  // b*N + j
        const int b = row >> 10, j = row & 1023;
        float re = 0.f, im = 0.f;
#pragma unroll
        for (int m = 0; m < 4; ++m) {
            const float rr = rowR[(b << 12) + (m << 10) + j];
            const float ri = rowI[(b << 12) + (m << 10) + j];
            re += rr * u[r][m] - ri * v[r][m];
            im += ri * u[r][m] + rr * v[r][m];
        }
        out[(size_t)row * 64 + lane] = re;
        out[524288 + (size_t)row * 64 + lane] = im;  // imag block
    }
}

extern "C" void kernel_launch(void* const* d_in, const int* in_sizes, int n_in,
                              void* d_out, int out_size, void* d_ws, size_t ws_size,
                              hipStream_t stream) {
    const float* Xr  = (const float*)d_in[0];
    const float* Xi  = (const float*)d_in[1];
    const float* Lr  = (const float*)d_in[2];
    const float* Li  = (const float*)d_in[3];
    const float* wr  = (const float*)d_in[4];
    const float* wi  = (const float*)d_in[5];
    const float* awr = (const float*)d_in[6];
    const float* awi = (const float*)d_in[7];
    const float* abr = (const float*)d_in[8];
    const float* abi = (const float*)d_in[9];
    const float* par = (const float*)d_in[10];
    const float* pai = (const float*)d_in[11];
    float* out = (float*)d_out;

    // Workspace layout (floats): sRi[8192] | sIi[8192] | aux float4[8192]
    //                            | rowR[32768] | rowI[32768]  => 448 KB total
    float*  ws   = (float*)d_ws;
    float*  sRi  = ws;
    float*  sIi  = ws + 8192;
    float4* aux  = (float4*)(ws + 16384);
    float*  rowR = ws + 49152;
    float*  rowI = ws + 81920;

    k_scores  <<<dim3(2048), dim3(256), 0, stream>>>(Xr, Xi, awr, awi, sRi, sIi, aux);
    k_softmax <<<dim3(2048), dim3(256), 0, stream>>>(sRi, sIi, aux, abr, abi, par, pai);
    k_rowreduce<<<dim3(2048), dim3(256), 0, stream>>>(Lr, Li, sRi, sIi, aux,
                                                      abr, abi, par, pai, rowR, rowI);
    k_output  <<<dim3(512),  dim3(256), 0, stream>>>(Xr, Xi, wr, wi, rowR, rowI, out);
}

// Round 2
// 341.917 us; speedup vs baseline: 1.0368x; 1.0368x over previous
//
#include <hip/hip_runtime.h>

// Problem constants: B=8, N=1024, C=64, O=64, K+1=4
#define EPS_Q 1e-12f

__device__ __forceinline__ float wave_reduce_sum(float v) {
#pragma unroll
    for (int m = 32; m > 0; m >>= 1) v += __shfl_xor(v, m, 64);
    return v;
}

// ---------------------------------------------------------------------------
// Kernel A: per-node attention scores. One wave per row (b*N+n), lane = c.
// sR_i = Xr·Wr_i - Xi·Wi_i ; sI_i = Xr·Wi_i + Xi·Wr_i ; same with _j weights.
// Writes sRi/sIi arrays and aux[row].x/.y = (sRj, sIj).
// ---------------------------------------------------------------------------
__global__ __launch_bounds__(256)
void k_scores(const float* __restrict__ Xr, const float* __restrict__ Xi,
              const float* __restrict__ awr, const float* __restrict__ awi,
              float* __restrict__ sRi, float* __restrict__ sIi,
              float4* __restrict__ aux) {
    const int lane = threadIdx.x & 63;
    const int row  = (blockIdx.x << 2) + (threadIdx.x >> 6);  // b*N + n
    const float xr = Xr[row * 64 + lane];
    const float xi = Xi[row * 64 + lane];
    const float wri = awr[lane], wrj = awr[64 + lane];
    const float wii = awi[lane], wij = awi[64 + lane];
    float v0 = xr * wri - xi * wii;   // sR_i partial
    float v1 = xr * wii + xi * wri;   // sI_i partial
    float v2 = xr * wrj - xi * wij;   // sR_j partial
    float v3 = xr * wij + xi * wrj;   // sI_j partial
#pragma unroll
    for (int m = 32; m > 0; m >>= 1) {
        v0 += __shfl_xor(v0, m, 64);
        v1 += __shfl_xor(v1, m, 64);
        v2 += __shfl_xor(v2, m, 64);
        v3 += __shfl_xor(v3, m, 64);
    }
    if (lane == 0) {
        sRi[row] = v0;
        sIi[row] = v1;
        aux[row].x = v2;
        aux[row].y = v3;
    }
}

// ---------------------------------------------------------------------------
// Kernel B: column softmax stats. softmax is over axis=1 (index i) for each
// (b, j). One wave per (b, j); lanes stride over i, 16 mags kept in regs.
// Writes aux[row].z = colmax, aux[row].w = 1/sum(exp(mag - colmax)).
// ---------------------------------------------------------------------------
__global__ __launch_bounds__(256)
void k_softmax(const float* __restrict__ sRi, const float* __restrict__ sIi,
               float4* __restrict__ aux,
               const float* __restrict__ abr, const float* __restrict__ abi,
               const float* __restrict__ par_, const float* __restrict__ pai_) {
    const int lane = threadIdx.x & 63;
    const int row  = (blockIdx.x << 2) + (threadIdx.x >> 6);  // b*N + j
    const int b    = row >> 10;
    const float br = abr[0], bi = abi[0], par = par_[0], pai = pai_[0];
    const float sRj = aux[row].x, sIj = aux[row].y;
    const float* pR = sRi + (b << 10);
    const float* pI = sIi + (b << 10);
    float mags[16];
    float mx = -3.4e38f;
#pragma unroll
    for (int t = 0; t < 16; ++t) {
        const int i = (t << 6) + lane;
        float sr = pR[i] + sRj + br;
        float si = pI[i] + sIj + bi;
        float pr = sr >= 0.f ? sr : par * sr;
        float pi = si >= 0.f ? si : pai * si;
        float mg = sqrtf(pr * pr + pi * pi);
        mags[t] = mg;
        mx = fmaxf(mx, mg);
    }
#pragma unroll
    for (int m = 32; m > 0; m >>= 1) mx = fmaxf(mx, __shfl_xor(mx, m, 64));
    float s = 0.f;
#pragma unroll
    for (int t = 0; t < 16; ++t) s += __expf(mags[t] - mx);
    s = wave_reduce_sum(s);
    if (lane == 0) {
        aux[row].z = mx;
        aux[row].w = 1.f / s;
    }
}

// ---------------------------------------------------------------------------
// Kernel C: the 268 MB streaming kernel, restructured for latency tolerance.
// Block <-> (b, i). Phase 1: the block's 256 threads cooperatively compute
// ar/ai[j] for the row's full j-range into LDS (coalesced aux float4 loads;
// all transcendentals here, OFF the streaming path). Phase 2: wave w streams
// k-slice w's Lr/Li row (2 contiguous 4 KB streams, 8 independent float4
// loads, fully unrolled) + ds_read_b128 of ar/ai, FMA, butterfly-reduce.
// Per wave: 2 streams (was 8), zero scattered loads (was 16 x 64-line).
// ---------------------------------------------------------------------------
__global__ __launch_bounds__(256)
void k_rowreduce(const float* __restrict__ Lr, const float* __restrict__ Li,
                 const float* __restrict__ sRi, const float* __restrict__ sIi,
                 const float4* __restrict__ aux,
                 const float* __restrict__ abr, const float* __restrict__ abi,
                 const float* __restrict__ par_, const float* __restrict__ pai_,
                 float* __restrict__ rowR, float* __restrict__ rowI) {
    __shared__ float lar[1024];
    __shared__ float lai[1024];
    const int tid = threadIdx.x;
    const int row = blockIdx.x;          // b*N + i
    const int b = row >> 10;
    const int i = row & 1023;
    const float br = abr[0], bi = abi[0], par = par_[0], pai = pai_[0];
    const float sri = sRi[row], sii = sIi[row];
    const float4* auxb = aux + (b << 10);

    // Phase 1: ar/ai for all 1024 j, 4 j per thread, coalesced.
#pragma unroll
    for (int t = 0; t < 4; ++t) {
        const int j = (t << 8) + tid;
        const float4 ax = auxb[j];          // (sRj, sIj, colmax, 1/colsum)
        float sr = sri + ax.x + br;
        float si = sii + ax.y + bi;
        float pr = sr >= 0.f ? sr : par * sr;
        float pi = si >= 0.f ? si : pai * si;
        float mg = sqrtf(pr * pr + pi * pi);
        float sc = __expf(mg - ax.z) * ax.w / (mg + EPS_Q);
        lar[j] = sc * pr;
        lai[j] = sc * pi;
    }
    __syncthreads();

    // Phase 2: wave w streams k-slice w.
    const int wave = tid >> 6, lane = tid & 63;
    const size_t base = ((size_t)((b * 4 + wave) * 1024 + i)) * 1024;
    const float4* LR = (const float4*)(Lr + base);
    const float4* LI = (const float4*)(Li + base);
    const float4* AR = (const float4*)lar;
    const float4* AI = (const float4*)lai;
    float aR = 0.f, aI = 0.f;
#pragma unroll
    for (int t = 0; t < 4; ++t) {
        const int j4 = (t << 6) + lane;
        const float4 lr = LR[j4];
        const float4 li = LI[j4];
        const float4 ar = AR[j4];
        const float4 ai = AI[j4];
        aR += lr.x * ar.x - li.x * ai.x;
        aR += lr.y * ar.y - li.y * ai.y;
        aR += lr.z * ar.z - li.z * ai.z;
        aR += lr.w * ar.w - li.w * ai.w;
        aI += lr.x * ai.x + li.x * ar.x;
        aI += lr.y * ai.y + li.y * ar.y;
        aI += lr.z * ai.z + li.z * ar.z;
        aI += lr.w * ai.w + li.w * ar.w;
    }
#pragma unroll
    for (int m = 32; m > 0; m >>= 1) {
        aR += __shfl_xor(aR, m, 64);
        aI += __shfl_xor(aI, m, 64);
    }
    if (lane == 0) {
        rowR[((b << 2) + wave) * 1024 + i] = aR;
        rowI[((b << 2) + wave) * 1024 + i] = aI;
    }
}

// ---------------------------------------------------------------------------
// Kernel D: out[b,j,o] = sum_m rowR[b,m,j]*(Xr[b,j]·wr[m,:,o])
//                      - sum_m rowI[b,m,j]*(Xi[b,j]·wi[m,:,o])   (real)
//           imag analogous. One wave handles 4 rows (register blocked) so the
//           128 KB of w is amortized; X rows staged in LDS (broadcast reads).
// ---------------------------------------------------------------------------
__global__ __launch_bounds__(256)
void k_output(const float* __restrict__ Xr, const float* __restrict__ Xi,
              const float* __restrict__ wr, const float* __restrict__ wi,
              const float* __restrict__ rowR, const float* __restrict__ rowI,
              float* __restrict__ out) {
    __shared__ float lxr[16][64];
    __shared__ float lxi[16][64];
    const int tid = threadIdx.x;
    const int rb  = blockIdx.x << 4;  // 16 rows per block
    {
        const float4* s0 = (const float4*)(Xr + (size_t)rb * 64);
        const float4* s1 = (const float4*)(Xi + (size_t)rb * 64);
        ((float4*)&lxr[0][0])[tid] = s0[tid];  // 16*64 floats = 256 float4
        ((float4*)&lxi[0][0])[tid] = s1[tid];
    }
    __syncthreads();
    const int wave = tid >> 6, lane = tid & 63;
    const int r0 = wave << 2;  // 4 rows per wave
    float u[4][4], v[4][4];
#pragma unroll
    for (int r = 0; r < 4; ++r)
#pragma unroll
        for (int m = 0; m < 4; ++m) { u[r][m] = 0.f; v[r][m] = 0.f; }
    for (int c = 0; c < 64; ++c) {
        float wrv[4], wiv[4];
#pragma unroll
        for (int m = 0; m < 4; ++m) {
            wrv[m] = wr[((m << 6) + c) * 64 + lane];
            wiv[m] = wi[((m << 6) + c) * 64 + lane];
        }
#pragma unroll
        for (int r = 0; r < 4; ++r) {
            const float xr = lxr[r0 + r][c];
            const float xi = lxi[r0 + r][c];
#pragma unroll
            for (int m = 0; m < 4; ++m) {
                u[r][m] += xr * wrv[m];
                v[r][m] += xi * wiv[m];
            }
        }
    }
#pragma unroll
    for (int r = 0; r < 4; ++r) {
        const int row = rb + r0 + r;  // b*N + j
        const int b = row >> 10, j = row & 1023;
        float re = 0.f, im = 0.f;
#pragma unroll
        for (int m = 0; m < 4; ++m) {
            const float rr = rowR[(b << 12) + (m << 10) + j];
            const float ri = rowI[(b << 12) + (m << 10) + j];
            re += rr * u[r][m] - ri * v[r][m];
            im += ri * u[r][m] + rr * v[r][m];
        }
        out[(size_t)row * 64 + lane] = re;
        out[524288 + (size_t)row * 64 + lane] = im;  // imag block
    }
}

extern "C" void kernel_launch(void* const* d_in, const int* in_sizes, int n_in,
                              void* d_out, int out_size, void* d_ws, size_t ws_size,
                              hipStream_t stream) {
    const float* Xr  = (const float*)d_in[0];
    const float* Xi  = (const float*)d_in[1];
    const float* Lr  = (const float*)d_in[2];
    const float* Li  = (const float*)d_in[3];
    const float* wr  = (const float*)d_in[4];
    const float* wi  = (const float*)d_in[5];
    const float* awr = (const float*)d_in[6];
    const float* awi = (const float*)d_in[7];
    const float* abr = (const float*)d_in[8];
    const float* abi = (const float*)d_in[9];
    const float* par = (const float*)d_in[10];
    const float* pai = (const float*)d_in[11];
    float* out = (float*)d_out;

    // Workspace layout (floats): sRi[8192] | sIi[8192] | aux float4[8192]
    //                            | rowR[32768] | rowI[32768]  => 448 KB total
    float*  ws   = (float*)d_ws;
    float*  sRi  = ws;
    float*  sIi  = ws + 8192;
    float4* aux  = (float4*)(ws + 16384);
    float*  rowR = ws + 49152;
    float*  rowI = ws + 81920;

    k_scores  <<<dim3(2048), dim3(256), 0, stream>>>(Xr, Xi, awr, awi, sRi, sIi, aux);
    k_softmax <<<dim3(2048), dim3(256), 0, stream>>>(sRi, sIi, aux, abr, abi, par, pai);
    k_rowreduce<<<dim3(8192), dim3(256), 0, stream>>>(Lr, Li, sRi, sIi, aux,
                                                      abr, abi, par, pai, rowR, rowI);
    k_output  <<<dim3(512),  dim3(256), 0, stream>>>(Xr, Xi, wr, wi, rowR, rowI, out);
}